// Round 8
// baseline (1801.635 us; speedup 1.0000x reference)
//
#include <hip/hip_runtime.h>

#define B 128
#define T 1500
#define NI 80        // N_MELS
#define H 128        // HIDDEN
#define G 384        // 3*H
#define TT 64        // t-tile for gx gemm

typedef float v2f __attribute__((ext_vector_type(2)));

__device__ __forceinline__ float sigf(float x) { return 1.0f / (1.0f + __expf(-x)); }
__device__ __forceinline__ float tanhfast(float x) { return 1.0f - 2.0f / (1.0f + __expf(2.0f * x)); }
__device__ __forceinline__ v2f pkfma(v2f a, v2f b, v2f c) { return __builtin_elementwise_fma(a, b, c); }

// butterfly sum over lanes xor1 + xor2 via DPP quad_perm (VALU pipe, ~8 cyc/level)
__device__ __forceinline__ float qsum(float v) {
    int a = __builtin_bit_cast(int, v);
    int b = __builtin_amdgcn_update_dpp(0, a, 0xB1, 0xF, 0xF, true);   // [1,0,3,2]
    float s = v + __builtin_bit_cast(float, b);
    int c = __builtin_bit_cast(int, s);
    int d = __builtin_amdgcn_update_dpp(0, c, 0x4E, 0xF, 0xF, true);   // [2,3,0,1]
    return s + __builtin_bit_cast(float, d);
}

// ---------------- gx GEMM (round-4 version, known-good ~285us) ----------------
__global__ __launch_bounds__(384)
void gx_gemm_kernel(const float* __restrict__ x, const float* __restrict__ w_ih,
                    const float* __restrict__ b_ih, float* __restrict__ gx,
                    int t0, int ct) {
    int tile = blockIdx.x;
    int b = blockIdx.y;
    int tl0 = tile * TT;
    if (tl0 >= ct) return;
    int n = (ct - tl0 < TT) ? (ct - tl0) : TT;
    int tid = threadIdx.x;  // = output g

    __shared__ __align__(16) float xs[TT * NI];   // 20 KB
    const float4* xsrc4 = (const float4*)(x + ((size_t)b * T + (size_t)(t0 + tl0)) * NI);
    int total4 = n * (NI / 4);
    for (int i = tid; i < total4; i += 384) ((float4*)xs)[i] = xsrc4[i];

    v2f w2[40];
    const v2f* wr = (const v2f*)(w_ih + (size_t)tid * NI);
#pragma unroll
    for (int i = 0; i < 40; ++i) w2[i] = wr[i];
    float bias = b_ih[tid];
    __syncthreads();

    float* gout = gx + ((size_t)b * ct + (size_t)tl0) * G + tid;
    int tt = 0;
    for (; tt + 2 <= n; tt += 2) {
        const float4* xa4 = (const float4*)(xs + tt * NI);
        const float4* xb4 = (const float4*)(xs + (tt + 1) * NI);
        v2f a0 = {0.f, 0.f}, a1 = {0.f, 0.f}, c0 = {0.f, 0.f}, c1 = {0.f, 0.f};
#pragma unroll
        for (int i = 0; i < 20; ++i) {
            float4 xa = xa4[i];
            float4 xb = xb4[i];
            v2f alo = {xa.x, xa.y}, ahi = {xa.z, xa.w};
            v2f blo = {xb.x, xb.y}, bhi = {xb.z, xb.w};
            a0 = pkfma(w2[2 * i], alo, a0);
            a1 = pkfma(w2[2 * i + 1], ahi, a1);
            c0 = pkfma(w2[2 * i], blo, c0);
            c1 = pkfma(w2[2 * i + 1], bhi, c1);
        }
        gout[(size_t)tt * G]       = bias + ((a0.x + a0.y) + (a1.x + a1.y));
        gout[(size_t)(tt + 1) * G] = bias + ((c0.x + c0.y) + (c1.x + c1.y));
    }
    if (tt < n) {
        const float4* xa4 = (const float4*)(xs + tt * NI);
        v2f a0 = {0.f, 0.f}, a1 = {0.f, 0.f};
#pragma unroll
        for (int i = 0; i < 20; ++i) {
            float4 xa = xa4[i];
            v2f alo = {xa.x, xa.y}, ahi = {xa.z, xa.w};
            a0 = pkfma(w2[2 * i], alo, a0);
            a1 = pkfma(w2[2 * i + 1], ahi, a1);
        }
        gout[(size_t)tt * G] = bias + ((a0.x + a0.y) + (a1.x + a1.y));
    }
}

// ---------------- scan: 2 batches per 1024-thread block ----------------
// half = tid>>9 selects batch; within a half: r4's proven layout — local = j*4+q,
// j in [0,128), q in [0,4), W_hh rows {j,j+H,j+2H} k-slice [32q,32q+32) packed in
// VGPRs (48 pkfma/step). 16 waves/CU = 4/SIMD: chain latency (ds_read, gates)
// pipelines 4-deep. DPP quad reduce (xor1+xor2, VALU pipe — no ds_bpermute on the
// chain). gx via distance-2 register prefetch; raw s_barrier + lgkmcnt-only wait.
__global__ __launch_bounds__(1024)
void scan_kernel(const float* __restrict__ gx, const float* __restrict__ w_hh,
                 const float* __restrict__ b_hh, float* __restrict__ h_state,
                 int ct, int first, int last,
                 const float* __restrict__ x,
                 const float* __restrict__ w_ih_b, const float* __restrict__ b_ih_b,
                 const float* __restrict__ b_hh_b,
                 const float* __restrict__ w1, const float* __restrict__ b1,
                 const float* __restrict__ w2, const float* __restrict__ b2,
                 float* __restrict__ out) {
    int tid = threadIdx.x;
    int half = tid >> 9;
    int b = blockIdx.x * 2 + half;
    int local = tid & 511;
    int j = local >> 2;
    int q = local & 3;
    int jpad = j + ((j >> 5) << 2);   // padded h index (36-float q-slice stride)

    __shared__ __align__(16) float hs[2][2][144];
    __shared__ __align__(16) float tail_gx[2][G];
    __shared__ __align__(16) float last_s[2][2 * H];
    __shared__ __align__(16) float xb_s[2][NI];

    // W_hh fragments (packed)
    v2f WR[16], WZ[16], WN[16];
    {
        const v2f* p0 = (const v2f*)(w_hh + (size_t)j * H + 32 * q);
        const v2f* p1 = (const v2f*)(w_hh + (size_t)(j + H) * H + 32 * q);
        const v2f* p2 = (const v2f*)(w_hh + (size_t)(j + 2 * H) * H + 32 * q);
#pragma unroll
        for (int i = 0; i < 16; ++i) { WR[i] = p0[i]; WZ[i] = p1[i]; WN[i] = p2[i]; }
    }
    float br = b_hh[j], bz = b_hh[j + H], bn = b_hh[j + 2 * H];

    float h_cur = 0.f;
    if (!first) h_cur = h_state[b * H + j];
    if (q == 0) hs[half][0][jpad] = h_cur;

    // gx prefetch registers, distance 2 (set A for even t, set B for odd t)
    float ga0, ga1, ga2, gb0 = 0.f, gb1 = 0.f, gb2 = 0.f;
    {
        const float* gp = gx + (size_t)b * ct * G;
        ga0 = gp[j]; ga1 = gp[j + H]; ga2 = gp[j + 2 * H];
        if (ct > 1) { gb0 = gp[G + j]; gb1 = gp[G + j + H]; gb2 = gp[G + j + 2 * H]; }
    }
    __syncthreads();   // prologue only

    auto step = [&](int TL, int SB, float& g0, float& g1, float& g2) {
        const float4* hv4 = (const float4*)(&hs[half][SB][0] + 36 * q);
        v2f arv = {0.f, 0.f}, azv = {0.f, 0.f}, anv = {0.f, 0.f};
#pragma unroll
        for (int i = 0; i < 8; ++i) {
            float4 hv = hv4[i];
            v2f hlo = {hv.x, hv.y}, hhi = {hv.z, hv.w};
            arv = pkfma(WR[2 * i], hlo, arv);
            azv = pkfma(WZ[2 * i], hlo, azv);
            anv = pkfma(WN[2 * i], hlo, anv);
            arv = pkfma(WR[2 * i + 1], hhi, arv);
            azv = pkfma(WZ[2 * i + 1], hhi, azv);
            anv = pkfma(WN[2 * i + 1], hhi, anv);
        }
        float ar = qsum(arv.x + arv.y);
        float az = qsum(azv.x + azv.y);
        float an = qsum(anv.x + anv.y);
        float r = sigf(g0 + br + ar);
        float z = sigf(g1 + bz + az);
        float n = tanhfast(g2 + r * (bn + an));
        h_cur = n + z * (h_cur - n);
        if (q == 0) hs[half][SB ^ 1][jpad] = h_cur;
        if (TL + 2 < ct) {
            const float* gp = gx + ((size_t)b * ct + TL + 2) * G;
            g0 = gp[j]; g1 = gp[j + H]; g2 = gp[j + 2 * H];
        }
        asm volatile("s_waitcnt lgkmcnt(0)\n\ts_barrier" ::: "memory");
    };

    int tl = 0;
    for (; tl + 1 < ct; tl += 2) {
        step(tl,     0, ga0, ga1, ga2);
        step(tl + 1, 1, gb0, gb1, gb2);
    }
    if (tl < ct) step(tl, 0, ga0, ga1, ga2);

    if (!last) {
        if (q == 0) h_state[b * H + j] = h_cur;
        return;
    }

    // ---- backward single step (h0 = 0) + MLP head, per half ----
    if (local < NI) xb_s[half][local] = x[((size_t)b * T + (T - 1)) * NI + local];
    if (q == 0) last_s[half][j] = h_cur;  // forward final hidden
    __syncthreads();

    if (local < G) {
        const float4* wbr = (const float4*)(w_ih_b + (size_t)local * NI);
        const float4* xv = (const float4*)xb_s[half];
        float a0 = 0.f, a1 = 0.f, a2 = 0.f, a3 = 0.f;
#pragma unroll
        for (int i = 0; i < 20; ++i) {
            float4 wv = wbr[i]; float4 x4 = xv[i];
            a0 = fmaf(wv.x, x4.x, a0); a1 = fmaf(wv.y, x4.y, a1);
            a2 = fmaf(wv.z, x4.z, a2); a3 = fmaf(wv.w, x4.w, a3);
        }
        tail_gx[half][local] = b_ih_b[local] + ((a0 + a1) + (a2 + a3));
    }
    __syncthreads();

    if (local < H) {
        float r = sigf(tail_gx[half][local] + b_hh_b[local]);
        float z = sigf(tail_gx[half][local + H] + b_hh_b[local + H]);
        float n = tanhfast(tail_gx[half][local + 2 * H] + r * b_hh_b[local + 2 * H]);
        last_s[half][H + local] = (1.f - z) * n;  // + z*0
    }
    __syncthreads();

    if (local < 64) {
        const float4* w1r = (const float4*)(w1 + (size_t)local * 2 * H);
        const float4* lv = (const float4*)last_s[half];
        float a0 = 0.f, a1 = 0.f, a2 = 0.f, a3 = 0.f;
#pragma unroll
        for (int i = 0; i < 64; ++i) {
            float4 wv = w1r[i]; float4 l4 = lv[i];
            a0 = fmaf(wv.x, l4.x, a0); a1 = fmaf(wv.y, l4.y, a1);
            a2 = fmaf(wv.z, l4.z, a2); a3 = fmaf(wv.w, l4.w, a3);
        }
        float v = b1[local] + ((a0 + a1) + (a2 + a3));
        v = fmaxf(v, 0.f) * w2[local];
#pragma unroll
        for (int off = 32; off > 0; off >>= 1) v += __shfl_down(v, off);
        if (local == 0) out[b] = v + b2[0];
    }
}

extern "C" void kernel_launch(void* const* d_in, const int* in_sizes, int n_in,
                              void* d_out, int out_size, void* d_ws, size_t ws_size,
                              hipStream_t stream) {
    (void)in_sizes; (void)n_in; (void)out_size;
    const float* x      = (const float*)d_in[0];
    const float* w_ih_f = (const float*)d_in[1];
    const float* w_hh_f = (const float*)d_in[2];
    const float* b_ih_f = (const float*)d_in[3];
    const float* b_hh_f = (const float*)d_in[4];
    const float* w_ih_b = (const float*)d_in[5];
    const float* w_hh_b = (const float*)d_in[6];  // unused: h0=0 makes gh_b = b_hh_b
    const float* b_ih_b = (const float*)d_in[7];
    const float* b_hh_b = (const float*)d_in[8];
    const float* w1     = (const float*)d_in[9];
    const float* b1     = (const float*)d_in[10];
    const float* w2     = (const float*)d_in[11];
    const float* b2     = (const float*)d_in[12];
    (void)w_hh_b;
    float* out = (float*)d_out;

    float* h_state = (float*)d_ws;                 // B*H floats
    float* gxbuf = h_state + B * H;
    size_t hbytes = (size_t)B * H * sizeof(float);
    size_t avail = ws_size > hbytes ? ws_size - hbytes : 0;
    long long chunkT = (long long)(avail / ((size_t)B * G * sizeof(float)));
    if (chunkT > T) chunkT = T;
    if (chunkT < 1) chunkT = 1;

    for (int t0 = 0; t0 < T; t0 += (int)chunkT) {
        int ct = (T - t0 < (int)chunkT) ? (T - t0) : (int)chunkT;
        int ntiles = (ct + TT - 1) / TT;
        gx_gemm_kernel<<<dim3(ntiles, B), dim3(384), 0, stream>>>(
            x, w_ih_f, b_ih_f, gxbuf, t0, ct);
        scan_kernel<<<dim3(B / 2), dim3(1024), 0, stream>>>(
            gxbuf, w_hh_f, b_hh_f, h_state, ct,
            (t0 == 0) ? 1 : 0, (t0 + ct >= T) ? 1 : 0,
            x, w_ih_b, b_ih_b, b_hh_b, w1, b1, w2, b2, out);
    }
}

// Round 9
// 1150.760 us; speedup vs baseline: 1.5656x; 1.5656x over previous
//
#include <hip/hip_runtime.h>

#define B 128
#define T 1500
#define NI 80        // N_MELS
#define H 128        // HIDDEN
#define G 384        // 3*H
#define TT 64        // t-tile for gx gemm

typedef float v2f __attribute__((ext_vector_type(2)));

__device__ __forceinline__ float sigf(float x) { return 1.0f / (1.0f + __expf(-x)); }
__device__ __forceinline__ float tanhfast(float x) { return 1.0f - 2.0f / (1.0f + __expf(2.0f * x)); }
__device__ __forceinline__ v2f pkfma(v2f a, v2f b, v2f c) { return __builtin_elementwise_fma(a, b, c); }

// sum over an aligned 8-lane group, entirely on the VALU pipe (DPP):
// half_mirror (i<->7-i), quad reverse [3,2,1,0], quad xor1 [1,0,3,2]
__device__ __forceinline__ float sum8(float v) {
    int a = __builtin_bit_cast(int, v);
    float m = __builtin_bit_cast(float, __builtin_amdgcn_update_dpp(0, a, 0x141, 0xF, 0xF, true));
    float s = v + m;
    a = __builtin_bit_cast(int, s);
    m = __builtin_bit_cast(float, __builtin_amdgcn_update_dpp(0, a, 0x1B, 0xF, 0xF, true));
    s = s + m;
    a = __builtin_bit_cast(int, s);
    m = __builtin_bit_cast(float, __builtin_amdgcn_update_dpp(0, a, 0xB1, 0xF, 0xF, true));
    return s + m;
}

// ---------------- gx GEMM (round-4 version, known-good ~285us) ----------------
__global__ __launch_bounds__(384)
void gx_gemm_kernel(const float* __restrict__ x, const float* __restrict__ w_ih,
                    const float* __restrict__ b_ih, float* __restrict__ gx,
                    int t0, int ct) {
    int tile = blockIdx.x;
    int b = blockIdx.y;
    int tl0 = tile * TT;
    if (tl0 >= ct) return;
    int n = (ct - tl0 < TT) ? (ct - tl0) : TT;
    int tid = threadIdx.x;  // = output g

    __shared__ __align__(16) float xs[TT * NI];   // 20 KB
    const float4* xsrc4 = (const float4*)(x + ((size_t)b * T + (size_t)(t0 + tl0)) * NI);
    int total4 = n * (NI / 4);
    for (int i = tid; i < total4; i += 384) ((float4*)xs)[i] = xsrc4[i];

    v2f w2[40];
    const v2f* wr = (const v2f*)(w_ih + (size_t)tid * NI);
#pragma unroll
    for (int i = 0; i < 40; ++i) w2[i] = wr[i];
    float bias = b_ih[tid];
    __syncthreads();

    float* gout = gx + ((size_t)b * ct + (size_t)tl0) * G + tid;
    int tt = 0;
    for (; tt + 2 <= n; tt += 2) {
        const float4* xa4 = (const float4*)(xs + tt * NI);
        const float4* xb4 = (const float4*)(xs + (tt + 1) * NI);
        v2f a0 = {0.f, 0.f}, a1 = {0.f, 0.f}, c0 = {0.f, 0.f}, c1 = {0.f, 0.f};
#pragma unroll
        for (int i = 0; i < 20; ++i) {
            float4 xa = xa4[i];
            float4 xb = xb4[i];
            v2f alo = {xa.x, xa.y}, ahi = {xa.z, xa.w};
            v2f blo = {xb.x, xb.y}, bhi = {xb.z, xb.w};
            a0 = pkfma(w2[2 * i], alo, a0);
            a1 = pkfma(w2[2 * i + 1], ahi, a1);
            c0 = pkfma(w2[2 * i], blo, c0);
            c1 = pkfma(w2[2 * i + 1], bhi, c1);
        }
        gout[(size_t)tt * G]       = bias + ((a0.x + a0.y) + (a1.x + a1.y));
        gout[(size_t)(tt + 1) * G] = bias + ((c0.x + c0.y) + (c1.x + c1.y));
    }
    if (tt < n) {
        const float4* xa4 = (const float4*)(xs + tt * NI);
        v2f a0 = {0.f, 0.f}, a1 = {0.f, 0.f};
#pragma unroll
        for (int i = 0; i < 20; ++i) {
            float4 xa = xa4[i];
            v2f alo = {xa.x, xa.y}, ahi = {xa.z, xa.w};
            a0 = pkfma(w2[2 * i], alo, a0);
            a1 = pkfma(w2[2 * i + 1], ahi, a1);
        }
        gout[(size_t)tt * G] = bias + ((a0.x + a0.y) + (a1.x + a1.y));
    }
}

// ---------------- scan ----------------
// 128 blocks x 512 threads (1 batch/block). tid = jp*8 + q, jp in [0,64), q in [0,8).
// Thread accumulates 6 partial dots (j=jp and j=jp+64, gates r/z/n) over k-slice
// [16q,16q+16): 4 ds_read_b128 per step (32 LDS inst/step/CU — half of r4).
// 8-lane butterfly reduce via DPP (VALU pipe). Lanes q<4 finalize gates for jp,
// q>=4 for jp+64 (one gate per lane). h slices padded to 20 floats: each read inst
// covers all 32 banks once (conflict-free). gx register prefetch distance 2;
// raw s_barrier + lgkmcnt-only wait (global loads stay in flight).
__global__ __launch_bounds__(512)
void scan_kernel(const float* __restrict__ gx, const float* __restrict__ w_hh,
                 const float* __restrict__ b_hh, float* __restrict__ h_state,
                 int ct, int first, int last,
                 const float* __restrict__ x,
                 const float* __restrict__ w_ih_b, const float* __restrict__ b_ih_b,
                 const float* __restrict__ b_hh_b,
                 const float* __restrict__ w1, const float* __restrict__ b1,
                 const float* __restrict__ w2, const float* __restrict__ b2,
                 float* __restrict__ out) {
    int b = blockIdx.x;
    int tid = threadIdx.x;
    int jp = tid >> 3;        // 0..63
    int q = tid & 7;          // 0..7
    int j0 = jp, j1 = jp + 64;
    int jsel = (q < 4) ? j0 : j1;
    int hsel = ((jsel >> 4) * 20) + (jsel & 15);   // padded LDS index of h[jsel]
    bool writer = (q & 3) == 0;                    // q==0 writes j0, q==4 writes j1

    __shared__ __align__(16) float hs[2][160];     // 8 slices x 20 floats
    __shared__ __align__(16) float tail_gx[G];
    __shared__ __align__(16) float last_s[2 * H];
    __shared__ __align__(16) float xb_s[NI];

    // W_hh fragments: rows {j0, j0+H, j0+2H, j1, j1+H, j1+2H}, k in [16q,16q+16)
    float4 W0r[4], W0z[4], W0n[4], W1r[4], W1z[4], W1n[4];
    {
        const float* wb = w_hh + 16 * q;
        const float4* p0 = (const float4*)(wb + (size_t)j0 * H);
        const float4* p1 = (const float4*)(wb + (size_t)(j0 + H) * H);
        const float4* p2 = (const float4*)(wb + (size_t)(j0 + 2 * H) * H);
        const float4* p3 = (const float4*)(wb + (size_t)j1 * H);
        const float4* p4 = (const float4*)(wb + (size_t)(j1 + H) * H);
        const float4* p5 = (const float4*)(wb + (size_t)(j1 + 2 * H) * H);
#pragma unroll
        for (int i = 0; i < 4; ++i) {
            W0r[i] = p0[i]; W0z[i] = p1[i]; W0n[i] = p2[i];
            W1r[i] = p3[i]; W1z[i] = p4[i]; W1n[i] = p5[i];
        }
    }
    float br = b_hh[jsel], bz = b_hh[jsel + H], bn = b_hh[jsel + 2 * H];

    float h_cur = 0.f;
    if (!first) h_cur = h_state[b * H + jsel];
    if (writer) hs[0][hsel] = h_cur;

    // gx prefetch registers for column jsel, distance 2 (set A even t, set B odd t)
    float ga0, ga1, ga2, gb0 = 0.f, gb1 = 0.f, gb2 = 0.f;
    {
        const float* gp = gx + (size_t)b * ct * G;
        ga0 = gp[jsel]; ga1 = gp[jsel + H]; ga2 = gp[jsel + 2 * H];
        if (ct > 1) { gb0 = gp[G + jsel]; gb1 = gp[G + jsel + H]; gb2 = gp[G + jsel + 2 * H]; }
    }
    __syncthreads();   // prologue only

    auto step = [&](int TL, int SB, float& g0, float& g1, float& g2) {
        const float4* hv4 = (const float4*)(&hs[SB][0] + 20 * q);
        float4 h0 = hv4[0], h1 = hv4[1], h2 = hv4[2], h3 = hv4[3];
        v2f a0r = {0.f, 0.f}, a0z = {0.f, 0.f}, a0n = {0.f, 0.f};
        v2f a1r = {0.f, 0.f}, a1z = {0.f, 0.f}, a1n = {0.f, 0.f};
        v2f hl, hh;
        hl = v2f{h0.x, h0.y}; hh = v2f{h0.z, h0.w};
        a0r = pkfma(v2f{W0r[0].x, W0r[0].y}, hl, a0r); a0r = pkfma(v2f{W0r[0].z, W0r[0].w}, hh, a0r);
        a0z = pkfma(v2f{W0z[0].x, W0z[0].y}, hl, a0z); a0z = pkfma(v2f{W0z[0].z, W0z[0].w}, hh, a0z);
        a0n = pkfma(v2f{W0n[0].x, W0n[0].y}, hl, a0n); a0n = pkfma(v2f{W0n[0].z, W0n[0].w}, hh, a0n);
        a1r = pkfma(v2f{W1r[0].x, W1r[0].y}, hl, a1r); a1r = pkfma(v2f{W1r[0].z, W1r[0].w}, hh, a1r);
        a1z = pkfma(v2f{W1z[0].x, W1z[0].y}, hl, a1z); a1z = pkfma(v2f{W1z[0].z, W1z[0].w}, hh, a1z);
        a1n = pkfma(v2f{W1n[0].x, W1n[0].y}, hl, a1n); a1n = pkfma(v2f{W1n[0].z, W1n[0].w}, hh, a1n);
        hl = v2f{h1.x, h1.y}; hh = v2f{h1.z, h1.w};
        a0r = pkfma(v2f{W0r[1].x, W0r[1].y}, hl, a0r); a0r = pkfma(v2f{W0r[1].z, W0r[1].w}, hh, a0r);
        a0z = pkfma(v2f{W0z[1].x, W0z[1].y}, hl, a0z); a0z = pkfma(v2f{W0z[1].z, W0z[1].w}, hh, a0z);
        a0n = pkfma(v2f{W0n[1].x, W0n[1].y}, hl, a0n); a0n = pkfma(v2f{W0n[1].z, W0n[1].w}, hh, a0n);
        a1r = pkfma(v2f{W1r[1].x, W1r[1].y}, hl, a1r); a1r = pkfma(v2f{W1r[1].z, W1r[1].w}, hh, a1r);
        a1z = pkfma(v2f{W1z[1].x, W1z[1].y}, hl, a1z); a1z = pkfma(v2f{W1z[1].z, W1z[1].w}, hh, a1z);
        a1n = pkfma(v2f{W1n[1].x, W1n[1].y}, hl, a1n); a1n = pkfma(v2f{W1n[1].z, W1n[1].w}, hh, a1n);
        hl = v2f{h2.x, h2.y}; hh = v2f{h2.z, h2.w};
        a0r = pkfma(v2f{W0r[2].x, W0r[2].y}, hl, a0r); a0r = pkfma(v2f{W0r[2].z, W0r[2].w}, hh, a0r);
        a0z = pkfma(v2f{W0z[2].x, W0z[2].y}, hl, a0z); a0z = pkfma(v2f{W0z[2].z, W0z[2].w}, hh, a0z);
        a0n = pkfma(v2f{W0n[2].x, W0n[2].y}, hl, a0n); a0n = pkfma(v2f{W0n[2].z, W0n[2].w}, hh, a0n);
        a1r = pkfma(v2f{W1r[2].x, W1r[2].y}, hl, a1r); a1r = pkfma(v2f{W1r[2].z, W1r[2].w}, hh, a1r);
        a1z = pkfma(v2f{W1z[2].x, W1z[2].y}, hl, a1z); a1z = pkfma(v2f{W1z[2].z, W1z[2].w}, hh, a1z);
        a1n = pkfma(v2f{W1n[2].x, W1n[2].y}, hl, a1n); a1n = pkfma(v2f{W1n[2].z, W1n[2].w}, hh, a1n);
        hl = v2f{h3.x, h3.y}; hh = v2f{h3.z, h3.w};
        a0r = pkfma(v2f{W0r[3].x, W0r[3].y}, hl, a0r); a0r = pkfma(v2f{W0r[3].z, W0r[3].w}, hh, a0r);
        a0z = pkfma(v2f{W0z[3].x, W0z[3].y}, hl, a0z); a0z = pkfma(v2f{W0z[3].z, W0z[3].w}, hh, a0z);
        a0n = pkfma(v2f{W0n[3].x, W0n[3].y}, hl, a0n); a0n = pkfma(v2f{W0n[3].z, W0n[3].w}, hh, a0n);
        a1r = pkfma(v2f{W1r[3].x, W1r[3].y}, hl, a1r); a1r = pkfma(v2f{W1r[3].z, W1r[3].w}, hh, a1r);
        a1z = pkfma(v2f{W1z[3].x, W1z[3].y}, hl, a1z); a1z = pkfma(v2f{W1z[3].z, W1z[3].w}, hh, a1z);
        a1n = pkfma(v2f{W1n[3].x, W1n[3].y}, hl, a1n); a1n = pkfma(v2f{W1n[3].z, W1n[3].w}, hh, a1n);

        float s0r = sum8(a0r.x + a0r.y), s0z = sum8(a0z.x + a0z.y), s0n = sum8(a0n.x + a0n.y);
        float s1r = sum8(a1r.x + a1r.y), s1z = sum8(a1z.x + a1z.y), s1n = sum8(a1n.x + a1n.y);
        bool lo = q < 4;
        float ar = lo ? s0r : s1r;
        float az = lo ? s0z : s1z;
        float an = lo ? s0n : s1n;
        float r = sigf(g0 + br + ar);
        float z = sigf(g1 + bz + az);
        float n = tanhfast(g2 + r * (bn + an));
        h_cur = n + z * (h_cur - n);
        if (writer) hs[SB ^ 1][hsel] = h_cur;
        if (TL + 2 < ct) {
            const float* gp = gx + ((size_t)b * ct + TL + 2) * G;
            g0 = gp[jsel]; g1 = gp[jsel + H]; g2 = gp[jsel + 2 * H];
        }
        asm volatile("s_waitcnt lgkmcnt(0)\n\ts_barrier" ::: "memory");
    };

    int tl = 0;
    for (; tl + 1 < ct; tl += 2) {
        step(tl,     0, ga0, ga1, ga2);
        step(tl + 1, 1, gb0, gb1, gb2);
    }
    if (tl < ct) step(tl, 0, ga0, ga1, ga2);

    if (!last) {
        if (writer) h_state[b * H + jsel] = h_cur;
        return;
    }

    // ---- backward single step (h0 = 0) + MLP head ----
    if (tid < NI) xb_s[tid] = x[((size_t)b * T + (T - 1)) * NI + tid];
    if (writer) last_s[jsel] = h_cur;  // forward final hidden
    __syncthreads();

    if (tid < G) {
        const float4* wbr = (const float4*)(w_ih_b + (size_t)tid * NI);
        const float4* xv = (const float4*)xb_s;
        float a0 = 0.f, a1 = 0.f, a2 = 0.f, a3 = 0.f;
#pragma unroll
        for (int i = 0; i < 20; ++i) {
            float4 wv = wbr[i]; float4 x4 = xv[i];
            a0 = fmaf(wv.x, x4.x, a0); a1 = fmaf(wv.y, x4.y, a1);
            a2 = fmaf(wv.z, x4.z, a2); a3 = fmaf(wv.w, x4.w, a3);
        }
        tail_gx[tid] = b_ih_b[tid] + ((a0 + a1) + (a2 + a3));
    }
    __syncthreads();

    if (tid < H) {
        float r = sigf(tail_gx[tid] + b_hh_b[tid]);
        float z = sigf(tail_gx[tid + H] + b_hh_b[tid + H]);
        float n = tanhfast(tail_gx[tid + 2 * H] + r * b_hh_b[tid + 2 * H]);
        last_s[H + tid] = (1.f - z) * n;  // + z*0
    }
    __syncthreads();

    if (tid < 64) {
        const float4* w1r = (const float4*)(w1 + (size_t)tid * 2 * H);
        const float4* lv = (const float4*)last_s;
        float a0 = 0.f, a1 = 0.f, a2 = 0.f, a3 = 0.f;
#pragma unroll
        for (int i = 0; i < 64; ++i) {
            float4 wv = w1r[i]; float4 l4 = lv[i];
            a0 = fmaf(wv.x, l4.x, a0); a1 = fmaf(wv.y, l4.y, a1);
            a2 = fmaf(wv.z, l4.z, a2); a3 = fmaf(wv.w, l4.w, a3);
        }
        float v = b1[tid] + ((a0 + a1) + (a2 + a3));
        v = fmaxf(v, 0.f) * w2[tid];
#pragma unroll
        for (int off = 32; off > 0; off >>= 1) v += __shfl_down(v, off);
        if (tid == 0) out[b] = v + b2[0];
    }
}

extern "C" void kernel_launch(void* const* d_in, const int* in_sizes, int n_in,
                              void* d_out, int out_size, void* d_ws, size_t ws_size,
                              hipStream_t stream) {
    (void)in_sizes; (void)n_in; (void)out_size;
    const float* x      = (const float*)d_in[0];
    const float* w_ih_f = (const float*)d_in[1];
    const float* w_hh_f = (const float*)d_in[2];
    const float* b_ih_f = (const float*)d_in[3];
    const float* b_hh_f = (const float*)d_in[4];
    const float* w_ih_b = (const float*)d_in[5];
    const float* w_hh_b = (const float*)d_in[6];  // unused: h0=0 makes gh_b = b_hh_b
    const float* b_ih_b = (const float*)d_in[7];
    const float* b_hh_b = (const float*)d_in[8];
    const float* w1     = (const float*)d_in[9];
    const float* b1     = (const float*)d_in[10];
    const float* w2     = (const float*)d_in[11];
    const float* b2     = (const float*)d_in[12];
    (void)w_hh_b;
    float* out = (float*)d_out;

    float* h_state = (float*)d_ws;                 // B*H floats
    float* gxbuf = h_state + B * H;
    size_t hbytes = (size_t)B * H * sizeof(float);
    size_t avail = ws_size > hbytes ? ws_size - hbytes : 0;
    long long chunkT = (long long)(avail / ((size_t)B * G * sizeof(float)));
    if (chunkT > T) chunkT = T;
    if (chunkT < 1) chunkT = 1;

    for (int t0 = 0; t0 < T; t0 += (int)chunkT) {
        int ct = (T - t0 < (int)chunkT) ? (T - t0) : (int)chunkT;
        int ntiles = (ct + TT - 1) / TT;
        gx_gemm_kernel<<<dim3(ntiles, B), dim3(384), 0, stream>>>(
            x, w_ih_f, b_ih_f, gxbuf, t0, ct);
        scan_kernel<<<dim3(B), dim3(512), 0, stream>>>(
            gxbuf, w_hh_f, b_hh_f, h_state, ct,
            (t0 == 0) ? 1 : 0, (t0 + ct >= T) ? 1 : 0,
            x, w_ih_b, b_ih_b, b_hh_b, w1, b1, w2, b2, out);
    }
}